// Round 1
// baseline (4830.670 us; speedup 1.0000x reference)
//
#include <hip/hip_runtime.h>

#define N_NODES 50000
#define N_EDGES 800000
#define IN_DIM 128
#define HIDDEN 256
#define N_CLASSES 10
#define N_GRAPHS 64

// ---------------- degree ----------------
__global__ void deg_count_kernel(const int* __restrict__ src, float* __restrict__ deg) {
    int e = blockIdx.x * blockDim.x + threadIdx.x;
    if (e < N_EDGES) atomicAdd(&deg[src[e]], 1.0f);
}

// deg -> rdeg in place: rdeg = deg>0 ? 1/deg : 0
__global__ void rdeg_kernel(float* deg) {
    int i = blockIdx.x * blockDim.x + threadIdx.x;
    if (i < N_NODES) { float d = deg[i]; deg[i] = d > 0.0f ? 1.0f / d : 0.0f; }
}

// ---------------- edge scatter: ns[src] += H[dst], D floats per edge ----------------
template<int D>
__global__ void scatter_kernel(const int* __restrict__ src, const int* __restrict__ dst,
                               const float* __restrict__ H, float* __restrict__ NS) {
    const int CH = D / 4;                       // float4 chunks per row
    int gid = blockIdx.x * blockDim.x + threadIdx.x;
    if (gid >= N_EDGES * CH) return;
    int e = gid / CH;
    int c = gid % CH;
    int s = src[e], d = dst[e];
    float4 v = reinterpret_cast<const float4*>(H)[(long)d * CH + c];
    float* p = NS + (long)s * D + c * 4;
    atomicAdd(p + 0, v.x); atomicAdd(p + 1, v.y);
    atomicAdd(p + 2, v.z); atomicAdd(p + 3, v.w);
}

// ---------------- fused layer GEMM ----------------
// out[row][col] = elu( x@Wg + (ns*rdeg)@Wl + mask*(x@Ws) + b )
// Implemented as K-concatenated GEMM: A = [X | NS*rdeg | m*X]  (K = 3*D), B = [Wg; Wl; Ws]
template<int D>
__global__ __launch_bounds__(256)
void gemm_layer_kernel(const float* __restrict__ X,    // [N_NODES][D]
                       const float* __restrict__ NS,   // [N_NODES][D] raw sums
                       const float* __restrict__ rdeg, // [N_NODES]
                       const float* __restrict__ Wg, const float* __restrict__ Wl,
                       const float* __restrict__ Ws,   // each [D][HIDDEN] row-major
                       const float* __restrict__ bias, // [HIDDEN]
                       float* __restrict__ OUT)        // [N_NODES][HIDDEN]
{
    const int BK = 16;
    __shared__ float As[BK][66];     // 64 rows + pad 2 (even pad keeps float2 alignment)
    __shared__ float Bs[BK][HIDDEN];

    const int rowbase = blockIdx.x * 64;
    const int tid = threadIdx.x;
    const int tx = tid & 31;   // col lane  (cols tx*2 + 64*jg)
    const int ty = tid >> 5;   // row group (rows ty*2 + 16*ig)

    float acc[8][8];
    #pragma unroll
    for (int i = 0; i < 8; ++i)
        #pragma unroll
        for (int j = 0; j < 8; ++j) acc[i][j] = 0.0f;

    // A loader: thread -> (k = tid&15, rows tid>>4 + 16p)
    const int a_k  = tid & 15;
    const int a_r0 = tid >> 4;
    // B loader: thread -> one float4 per pass, row tid>>6 + 4p, col4 tid&63
    const int b_c4 = tid & 63;
    const int b_r  = tid >> 6;

    const int KTOT = 3 * D;
    for (int kt = 0; kt < KTOT; kt += BK) {
        const int seg = kt / D;              // tile never straddles a segment (D%16==0)
        const int kd0 = kt - seg * D;

        // --- load A tile (64 x BK), transposed into As[k][row] ---
        #pragma unroll
        for (int p = 0; p < 4; ++p) {
            int rl = a_r0 + p * 16;
            int row = rowbase + rl;
            float v = 0.0f;
            if (row < N_NODES) {
                int kd = kd0 + a_k;
                if (seg == 0)      v = X[(long)row * D + kd];
                else if (seg == 1) v = NS[(long)row * D + kd] * rdeg[row];
                else               v = (rdeg[row] > 0.0f) ? X[(long)row * D + kd] : 0.0f;
            }
            As[a_k][rl] = v;
        }
        // --- load B tile (BK x 256) ---
        const float* W = (seg == 0) ? Wg : (seg == 1) ? Wl : Ws;
        const float4* W4 = reinterpret_cast<const float4*>(W);
        #pragma unroll
        for (int p = 0; p < 4; ++p) {
            int kr = b_r + p * 4;
            float4 w = W4[(long)(kd0 + kr) * (HIDDEN / 4) + b_c4];
            *reinterpret_cast<float4*>(&Bs[kr][b_c4 * 4]) = w;
        }
        __syncthreads();

        #pragma unroll
        for (int kk = 0; kk < BK; ++kk) {
            float a[8], bb[8];
            #pragma unroll
            for (int ig = 0; ig < 4; ++ig) {
                float2 t = *reinterpret_cast<const float2*>(&As[kk][ty * 2 + 16 * ig]);
                a[ig * 2] = t.x; a[ig * 2 + 1] = t.y;
            }
            #pragma unroll
            for (int jg = 0; jg < 4; ++jg) {
                float2 t = *reinterpret_cast<const float2*>(&Bs[kk][tx * 2 + 64 * jg]);
                bb[jg * 2] = t.x; bb[jg * 2 + 1] = t.y;
            }
            #pragma unroll
            for (int i = 0; i < 8; ++i)
                #pragma unroll
                for (int j = 0; j < 8; ++j)
                    acc[i][j] = fmaf(a[i], bb[j], acc[i][j]);
        }
        __syncthreads();
    }

    // --- epilogue: + bias, ELU, store ---
    #pragma unroll
    for (int ig = 0; ig < 4; ++ig) {
        #pragma unroll
        for (int ir = 0; ir < 2; ++ir) {
            int row = rowbase + ty * 2 + 16 * ig + ir;
            if (row >= N_NODES) continue;
            #pragma unroll
            for (int jg = 0; jg < 4; ++jg) {
                int col = tx * 2 + 64 * jg;
                float z0 = acc[ig * 2 + ir][jg * 2 + 0] + bias[col];
                float z1 = acc[ig * 2 + ir][jg * 2 + 1] + bias[col + 1];
                z0 = z0 > 0.0f ? z0 : (expf(z0) - 1.0f);
                z1 = z1 > 0.0f ? z1 : (expf(z1) - 1.0f);
                float2 st; st.x = z0; st.y = z1;
                *reinterpret_cast<float2*>(&OUT[(long)row * HIDDEN + col]) = st;
            }
        }
    }
}

// ---------------- mean pool per graph + classifier ----------------
__global__ void pool_classify_kernel(const float* __restrict__ H, const int* __restrict__ batch,
                                     const float* __restrict__ Wc, const float* __restrict__ bc,
                                     float* __restrict__ out) {
    __shared__ int s_lo, s_hi;
    __shared__ float pooled[HIDDEN];
    int g = blockIdx.x;
    if (threadIdx.x == 0) {
        int lo = 0, hi = N_NODES;
        while (lo < hi) { int m = (lo + hi) >> 1; if (batch[m] < g) lo = m + 1; else hi = m; }
        s_lo = lo;
        int lo2 = lo, hi2 = N_NODES;
        while (lo2 < hi2) { int m = (lo2 + hi2) >> 1; if (batch[m] < g + 1) lo2 = m + 1; else hi2 = m; }
        s_hi = lo2;
    }
    __syncthreads();
    int lo = s_lo, hi = s_hi;
    int t = threadIdx.x;
    float sum = 0.0f;
    for (int r = lo; r < hi; ++r) sum += H[(long)r * HIDDEN + t];
    float cnt = (float)(hi - lo);
    pooled[t] = sum / fmaxf(cnt, 1.0f);
    __syncthreads();
    if (t < N_CLASSES) {
        float accv = bc[t];
        #pragma unroll 4
        for (int k = 0; k < HIDDEN; ++k) accv = fmaf(pooled[k], Wc[k * N_CLASSES + t], accv);
        out[g * N_CLASSES + t] = accv;
    }
}

extern "C" void kernel_launch(void* const* d_in, const int* in_sizes, int n_in,
                              void* d_out, int out_size, void* d_ws, size_t ws_size,
                              hipStream_t stream) {
    const float* x    = (const float*)d_in[0];
    const int*   ei   = (const int*)d_in[1];
    const int*   batch= (const int*)d_in[2];
    const float* Wg0  = (const float*)d_in[3];
    const float* Wl0  = (const float*)d_in[4];
    const float* Ws0  = (const float*)d_in[5];
    const float* b0   = (const float*)d_in[6];
    const float* Wg1  = (const float*)d_in[7];
    const float* Wl1  = (const float*)d_in[8];
    const float* Ws1  = (const float*)d_in[9];
    const float* b1   = (const float*)d_in[10];
    const float* Wc   = (const float*)d_in[11];
    const float* bc   = (const float*)d_in[12];
    const int* src = ei;
    const int* dst = ei + N_EDGES;

    char* ws = (char*)d_ws;
    const size_t DEG_BYTES = 204800;                    // 50000 f32, padded
    const size_t NS_BYTES  = (size_t)N_NODES * HIDDEN * 4;  // 51.2 MB
    float* deg = (float*)ws;
    float* ns  = (float*)(ws + DEG_BYTES);
    float* h1  = (float*)(ws + DEG_BYTES + NS_BYTES);

    // zero deg + ns in one shot
    hipMemsetAsync(ws, 0, DEG_BYTES + NS_BYTES, stream);

    deg_count_kernel<<<(N_EDGES + 255) / 256, 256, 0, stream>>>(src, deg);
    rdeg_kernel<<<(N_NODES + 255) / 256, 256, 0, stream>>>(deg);

    // layer 0: scatter x -> ns (stride 128), fused GEMM -> h1
    {
        int total = N_EDGES * (IN_DIM / 4);
        scatter_kernel<IN_DIM><<<(total + 255) / 256, 256, 0, stream>>>(src, dst, x, ns);
    }
    gemm_layer_kernel<IN_DIM><<<(N_NODES + 63) / 64, 256, 0, stream>>>(
        x, ns, deg, Wg0, Wl0, Ws0, b0, h1);

    // layer 1: re-zero ns, scatter h1 -> ns (stride 256), fused GEMM in-place -> ns
    hipMemsetAsync(ns, 0, NS_BYTES, stream);
    {
        int total = N_EDGES * (HIDDEN / 4);
        scatter_kernel<HIDDEN><<<(total + 255) / 256, 256, 0, stream>>>(src, dst, h1, ns);
    }
    gemm_layer_kernel<HIDDEN><<<(N_NODES + 63) / 64, 256, 0, stream>>>(
        h1, ns, deg, Wg1, Wl1, Ws1, b1, ns);

    // pool + classify
    pool_classify_kernel<<<N_GRAPHS, HIDDEN, 0, stream>>>(ns, batch, Wc, bc, (float*)d_out);
}

// Round 2
// 1068.020 us; speedup vs baseline: 4.5230x; 4.5230x over previous
//
#include <hip/hip_runtime.h>

#define N_NODES 50000
#define N_EDGES 800000
#define IN_DIM 128
#define HIDDEN 256
#define N_CLASSES 10
#define N_GRAPHS 64

// ---------------- degree count (int) ----------------
__global__ void deg_count_kernel(const int* __restrict__ src, int* __restrict__ deg) {
    int e = blockIdx.x * blockDim.x + threadIdx.x;
    if (e < N_EDGES) atomicAdd(&deg[src[e]], 1);
}

// ---------------- single-block scan: rowptr (exclusive), cursor copy, rdeg ----------------
__global__ __launch_bounds__(1024)
void scan_kernel(const int* __restrict__ deg, int* __restrict__ rowptr,
                 int* __restrict__ cursor, float* __restrict__ rdeg) {
    __shared__ int buf[1024];
    __shared__ int carry;
    if (threadIdx.x == 0) { carry = 0; rowptr[0] = 0; }
    __syncthreads();
    for (int base = 0; base < N_NODES; base += 1024) {
        int i = base + threadIdx.x;
        int v = (i < N_NODES) ? deg[i] : 0;
        buf[threadIdx.x] = v;
        __syncthreads();
        #pragma unroll
        for (int off = 1; off < 1024; off <<= 1) {
            int t = (threadIdx.x >= off) ? buf[threadIdx.x - off] : 0;
            __syncthreads();
            buf[threadIdx.x] += t;
            __syncthreads();
        }
        int incl = buf[threadIdx.x] + carry;
        if (i < N_NODES) {
            rowptr[i + 1] = incl;
            cursor[i] = incl - v;   // exclusive prefix = fill cursor start
            rdeg[i] = (v > 0) ? 1.0f / (float)v : 0.0f;
        }
        __syncthreads();
        if (threadIdx.x == 1023) carry = incl;
        __syncthreads();
    }
}

// ---------------- CSR fill ----------------
__global__ void csr_fill_kernel(const int* __restrict__ src, const int* __restrict__ dst,
                                int* __restrict__ cursor, int* __restrict__ csr) {
    int e = blockIdx.x * blockDim.x + threadIdx.x;
    if (e < N_EDGES) {
        int p = atomicAdd(&cursor[src[e]], 1);
        csr[p] = dst[e];
    }
}

// ---------------- gather: NS[n] = mean over neighbors of H[dst] ----------------
// one wave (64 lanes) per node; D=256 -> float4/lane, D=128 -> float2/lane
template<int D>
__global__ __launch_bounds__(256)
void gather_mean_kernel(const int* __restrict__ rowptr, const int* __restrict__ csr,
                        const float* __restrict__ rdeg,
                        const float* __restrict__ H, float* __restrict__ NS) {
    int node = blockIdx.x * 4 + (threadIdx.x >> 6);
    if (node >= N_NODES) return;
    int lane = threadIdx.x & 63;
    int lo = rowptr[node], hi = rowptr[node + 1];
    float r = rdeg[node];
    if (D == 256) {
        const float4* H4 = reinterpret_cast<const float4*>(H);
        float4 acc = {0.f, 0.f, 0.f, 0.f};
        int j = lo;
        for (; j + 3 < hi; j += 4) {
            int d0 = csr[j], d1 = csr[j+1], d2 = csr[j+2], d3 = csr[j+3];
            float4 v0 = H4[(long)d0 * 64 + lane];
            float4 v1 = H4[(long)d1 * 64 + lane];
            float4 v2 = H4[(long)d2 * 64 + lane];
            float4 v3 = H4[(long)d3 * 64 + lane];
            acc.x += v0.x + v1.x + v2.x + v3.x;
            acc.y += v0.y + v1.y + v2.y + v3.y;
            acc.z += v0.z + v1.z + v2.z + v3.z;
            acc.w += v0.w + v1.w + v2.w + v3.w;
        }
        for (; j < hi; ++j) {
            int d = csr[j];
            float4 v = H4[(long)d * 64 + lane];
            acc.x += v.x; acc.y += v.y; acc.z += v.z; acc.w += v.w;
        }
        acc.x *= r; acc.y *= r; acc.z *= r; acc.w *= r;
        reinterpret_cast<float4*>(NS)[(long)node * 64 + lane] = acc;
    } else {
        const float2* H2 = reinterpret_cast<const float2*>(H);
        float2 acc = {0.f, 0.f};
        int j = lo;
        for (; j + 3 < hi; j += 4) {
            int d0 = csr[j], d1 = csr[j+1], d2 = csr[j+2], d3 = csr[j+3];
            float2 v0 = H2[(long)d0 * 64 + lane];
            float2 v1 = H2[(long)d1 * 64 + lane];
            float2 v2 = H2[(long)d2 * 64 + lane];
            float2 v3 = H2[(long)d3 * 64 + lane];
            acc.x += v0.x + v1.x + v2.x + v3.x;
            acc.y += v0.y + v1.y + v2.y + v3.y;
        }
        for (; j < hi; ++j) {
            int d = csr[j];
            float2 v = H2[(long)d * 64 + lane];
            acc.x += v.x; acc.y += v.y;
        }
        acc.x *= r; acc.y *= r;
        reinterpret_cast<float2*>(NS)[(long)node * 64 + lane] = acc;
    }
}

// ---------------- fused layer GEMM ----------------
// out = elu( X@Wg + NS@Wl + mask*(X@Ws) + b ), NS already holds the neighbor MEAN
template<int D>
__global__ __launch_bounds__(256)
void gemm_layer_kernel(const float* __restrict__ X,    // [N_NODES][D]
                       const float* __restrict__ NS,   // [N_NODES][D] neighbor means
                       const float* __restrict__ rdeg, // [N_NODES] (mask: >0)
                       const float* __restrict__ Wg, const float* __restrict__ Wl,
                       const float* __restrict__ Ws,   // each [D][HIDDEN] row-major
                       const float* __restrict__ bias, // [HIDDEN]
                       float* __restrict__ OUT)        // [N_NODES][HIDDEN]
{
    const int BK = 16;
    __shared__ float As[BK][66];
    __shared__ float Bs[BK][HIDDEN];

    const int rowbase = blockIdx.x * 64;
    const int tid = threadIdx.x;
    const int tx = tid & 31;
    const int ty = tid >> 5;

    float acc[8][8];
    #pragma unroll
    for (int i = 0; i < 8; ++i)
        #pragma unroll
        for (int j = 0; j < 8; ++j) acc[i][j] = 0.0f;

    const int a_k  = tid & 15;
    const int a_r0 = tid >> 4;
    const int b_c4 = tid & 63;
    const int b_r  = tid >> 6;

    const int KTOT = 3 * D;
    for (int kt = 0; kt < KTOT; kt += BK) {
        const int seg = kt / D;
        const int kd0 = kt - seg * D;

        #pragma unroll
        for (int p = 0; p < 4; ++p) {
            int rl = a_r0 + p * 16;
            int row = rowbase + rl;
            float v = 0.0f;
            if (row < N_NODES) {
                int kd = kd0 + a_k;
                if (seg == 0)      v = X[(long)row * D + kd];
                else if (seg == 1) v = NS[(long)row * D + kd];
                else               v = (rdeg[row] > 0.0f) ? X[(long)row * D + kd] : 0.0f;
            }
            As[a_k][rl] = v;
        }
        const float* W = (seg == 0) ? Wg : (seg == 1) ? Wl : Ws;
        const float4* W4 = reinterpret_cast<const float4*>(W);
        #pragma unroll
        for (int p = 0; p < 4; ++p) {
            int kr = b_r + p * 4;
            float4 w = W4[(long)(kd0 + kr) * (HIDDEN / 4) + b_c4];
            *reinterpret_cast<float4*>(&Bs[kr][b_c4 * 4]) = w;
        }
        __syncthreads();

        #pragma unroll
        for (int kk = 0; kk < BK; ++kk) {
            float a[8], bb[8];
            #pragma unroll
            for (int ig = 0; ig < 4; ++ig) {
                float2 t = *reinterpret_cast<const float2*>(&As[kk][ty * 2 + 16 * ig]);
                a[ig * 2] = t.x; a[ig * 2 + 1] = t.y;
            }
            #pragma unroll
            for (int jg = 0; jg < 4; ++jg) {
                float2 t = *reinterpret_cast<const float2*>(&Bs[kk][tx * 2 + 64 * jg]);
                bb[jg * 2] = t.x; bb[jg * 2 + 1] = t.y;
            }
            #pragma unroll
            for (int i = 0; i < 8; ++i)
                #pragma unroll
                for (int j = 0; j < 8; ++j)
                    acc[i][j] = fmaf(a[i], bb[j], acc[i][j]);
        }
        __syncthreads();
    }

    #pragma unroll
    for (int ig = 0; ig < 4; ++ig) {
        #pragma unroll
        for (int ir = 0; ir < 2; ++ir) {
            int row = rowbase + ty * 2 + 16 * ig + ir;
            if (row >= N_NODES) continue;
            #pragma unroll
            for (int jg = 0; jg < 4; ++jg) {
                int col = tx * 2 + 64 * jg;
                float z0 = acc[ig * 2 + ir][jg * 2 + 0] + bias[col];
                float z1 = acc[ig * 2 + ir][jg * 2 + 1] + bias[col + 1];
                z0 = z0 > 0.0f ? z0 : (expf(z0) - 1.0f);
                z1 = z1 > 0.0f ? z1 : (expf(z1) - 1.0f);
                float2 st; st.x = z0; st.y = z1;
                *reinterpret_cast<float2*>(&OUT[(long)row * HIDDEN + col]) = st;
            }
        }
    }
}

// ---------------- mean pool per graph + classifier ----------------
__global__ void pool_classify_kernel(const float* __restrict__ H, const int* __restrict__ batch,
                                     const float* __restrict__ Wc, const float* __restrict__ bc,
                                     float* __restrict__ out) {
    __shared__ int s_lo, s_hi;
    __shared__ float pooled[HIDDEN];
    int g = blockIdx.x;
    if (threadIdx.x == 0) {
        int lo = 0, hi = N_NODES;
        while (lo < hi) { int m = (lo + hi) >> 1; if (batch[m] < g) lo = m + 1; else hi = m; }
        s_lo = lo;
        int lo2 = lo, hi2 = N_NODES;
        while (lo2 < hi2) { int m = (lo2 + hi2) >> 1; if (batch[m] < g + 1) lo2 = m + 1; else hi2 = m; }
        s_hi = lo2;
    }
    __syncthreads();
    int lo = s_lo, hi = s_hi;
    int t = threadIdx.x;
    float sum = 0.0f;
    for (int r = lo; r < hi; ++r) sum += H[(long)r * HIDDEN + t];
    float cnt = (float)(hi - lo);
    pooled[t] = sum / fmaxf(cnt, 1.0f);
    __syncthreads();
    if (t < N_CLASSES) {
        float accv = bc[t];
        #pragma unroll 4
        for (int k = 0; k < HIDDEN; ++k) accv = fmaf(pooled[k], Wc[k * N_CLASSES + t], accv);
        out[g * N_CLASSES + t] = accv;
    }
}

extern "C" void kernel_launch(void* const* d_in, const int* in_sizes, int n_in,
                              void* d_out, int out_size, void* d_ws, size_t ws_size,
                              hipStream_t stream) {
    const float* x    = (const float*)d_in[0];
    const int*   ei   = (const int*)d_in[1];
    const int*   batch= (const int*)d_in[2];
    const float* Wg0  = (const float*)d_in[3];
    const float* Wl0  = (const float*)d_in[4];
    const float* Ws0  = (const float*)d_in[5];
    const float* b0   = (const float*)d_in[6];
    const float* Wg1  = (const float*)d_in[7];
    const float* Wl1  = (const float*)d_in[8];
    const float* Ws1  = (const float*)d_in[9];
    const float* b1   = (const float*)d_in[10];
    const float* Wc   = (const float*)d_in[11];
    const float* bc   = (const float*)d_in[12];
    const int* src = ei;
    const int* dst = ei + N_EDGES;

    char* ws = (char*)d_ws;
    // layout (bytes):
    //   deg    int[50000]   @ 0
    //   rdeg   f32[50000]   @ 262144
    //   rowptr int[50001]   @ 524288
    //   cursor int[50000]   @ 786432
    //   csr    int[800000]  @ 1048576
    //   ns     f32[50000*256] @ 4259840   (51.2 MB)
    //   h1     f32[50000*256] @ 55459840  (51.2 MB)  -> total ~106.7 MB
    int*   deg    = (int*)(ws + 0);
    float* rdeg   = (float*)(ws + 262144);
    int*   rowptr = (int*)(ws + 524288);
    int*   cursor = (int*)(ws + 786432);
    int*   csr    = (int*)(ws + 1048576);
    float* ns     = (float*)(ws + 4259840);
    float* h1     = (float*)(ws + 55459840);

    // zero degree counts only (everything else fully overwritten)
    hipMemsetAsync(deg, 0, (size_t)N_NODES * 4, stream);

    // build CSR
    deg_count_kernel<<<(N_EDGES + 255) / 256, 256, 0, stream>>>(src, deg);
    scan_kernel<<<1, 1024, 0, stream>>>(deg, rowptr, cursor, rdeg);
    csr_fill_kernel<<<(N_EDGES + 255) / 256, 256, 0, stream>>>(src, dst, cursor, csr);

    // layer 0: gather mean of x -> ns (D=128), fused GEMM -> h1
    gather_mean_kernel<IN_DIM><<<(N_NODES + 3) / 4, 256, 0, stream>>>(rowptr, csr, rdeg, x, ns);
    gemm_layer_kernel<IN_DIM><<<(N_NODES + 63) / 64, 256, 0, stream>>>(
        x, ns, rdeg, Wg0, Wl0, Ws0, b0, h1);

    // layer 1: gather mean of h1 -> ns (D=256), fused GEMM in-place -> ns
    gather_mean_kernel<HIDDEN><<<(N_NODES + 3) / 4, 256, 0, stream>>>(rowptr, csr, rdeg, h1, ns);
    gemm_layer_kernel<HIDDEN><<<(N_NODES + 63) / 64, 256, 0, stream>>>(
        h1, ns, rdeg, Wg1, Wl1, Ws1, b1, ns);

    // pool + classify
    pool_classify_kernel<<<N_GRAPHS, HIDDEN, 0, stream>>>(ns, batch, Wc, bc, (float*)d_out);
}

// Round 3
// 575.879 us; speedup vs baseline: 8.3883x; 1.8546x over previous
//
#include <hip/hip_runtime.h>

#define N_NODES 50000
#define N_PAD   50048          // padded row count (multiple of 128)
#define N_EDGES 800000
#define IN_DIM 128
#define HIDDEN 256
#define N_CLASSES 10
#define N_GRAPHS 64

typedef __attribute__((ext_vector_type(8))) short short8;
typedef __attribute__((ext_vector_type(4))) float f32x4;

__device__ __forceinline__ float bf2f(unsigned short h) {
    union { unsigned int u; float f; } v; v.u = ((unsigned int)h) << 16; return v.f;
}
__device__ __forceinline__ unsigned short f2bf(float f) {
    union { float f; unsigned int u; } v; v.f = f;
    unsigned int u = v.u;
    u += 0x7FFFu + ((u >> 16) & 1u);   // round to nearest even
    return (unsigned short)(u >> 16);
}

// ---------------- degree count ----------------
__global__ void deg_count_kernel(const int* __restrict__ src, int* __restrict__ deg) {
    int e = blockIdx.x * blockDim.x + threadIdx.x;
    if (e < N_EDGES) atomicAdd(&deg[src[e]], 1);
}

// ---------------- scan: rowptr, cursor, rdeg, deg0 list ----------------
__global__ __launch_bounds__(1024)
void scan_kernel(const int* __restrict__ deg, int* __restrict__ rowptr,
                 int* __restrict__ cursor, float* __restrict__ rdeg,
                 int* __restrict__ d0cnt, int* __restrict__ d0list) {
    __shared__ int buf[1024];
    __shared__ int carry;
    if (threadIdx.x == 0) { carry = 0; rowptr[0] = 0; }
    __syncthreads();
    for (int base = 0; base < N_NODES; base += 1024) {
        int i = base + threadIdx.x;
        int v = (i < N_NODES) ? deg[i] : 0;
        buf[threadIdx.x] = v;
        __syncthreads();
        #pragma unroll
        for (int off = 1; off < 1024; off <<= 1) {
            int t = (threadIdx.x >= off) ? buf[threadIdx.x - off] : 0;
            __syncthreads();
            buf[threadIdx.x] += t;
            __syncthreads();
        }
        int incl = buf[threadIdx.x] + carry;
        if (i < N_NODES) {
            rowptr[i + 1] = incl;
            cursor[i] = incl - v;
            rdeg[i] = (v > 0) ? 1.0f / (float)v : 0.0f;
            if (v == 0) { int p = atomicAdd(d0cnt, 1); d0list[p] = i; }
        }
        __syncthreads();
        if (threadIdx.x == 1023) carry = incl;
        __syncthreads();
    }
}

// ---------------- CSR fill ----------------
__global__ void csr_fill_kernel(const int* __restrict__ src, const int* __restrict__ dst,
                                int* __restrict__ cursor, int* __restrict__ csr) {
    int e = blockIdx.x * blockDim.x + threadIdx.x;
    if (e < N_EDGES) {
        int p = atomicAdd(&cursor[src[e]], 1);
        csr[p] = dst[e];
    }
}

// ---------------- fp32 -> bf16 convert (4 at a time) ----------------
__global__ void cvt_bf16_kernel(const float* __restrict__ in, unsigned short* __restrict__ out, int n4) {
    int i = blockIdx.x * blockDim.x + threadIdx.x;
    if (i >= n4) return;
    float4 v = reinterpret_cast<const float4*>(in)[i];
    ushort4 o;
    o.x = f2bf(v.x); o.y = f2bf(v.y); o.z = f2bf(v.z); o.w = f2bf(v.w);
    reinterpret_cast<ushort4*>(out)[i] = o;
}

// ---------------- weight prep: Wt[c][k] = bf16( k<D ? Wg[k][c]+Ws[k][c] : Wl[k-D][c] ) ----------------
template<int D>
__global__ void prep_w_kernel(const float* __restrict__ Wg, const float* __restrict__ Wl,
                              const float* __restrict__ Ws, unsigned short* __restrict__ Wt) {
    int i = blockIdx.x * blockDim.x + threadIdx.x;
    if (i >= 256 * 2 * D) return;
    int c = i / (2 * D), k = i % (2 * D);
    float v;
    if (k < D) v = Wg[(size_t)k * 256 + c] + Ws[(size_t)k * 256 + c];
    else       v = Wl[(size_t)(k - D) * 256 + c];
    Wt[i] = f2bf(v);
}

// ---------------- gather mean (bf16 in, bf16 out), one wave per node ----------------
// D=128: one uint (2 bf16)/lane; D=256: one uint2 (4 bf16)/lane
template<int D>
__global__ __launch_bounds__(256)
void gather_mean_kernel(const int* __restrict__ rowptr, const int* __restrict__ csr,
                        const float* __restrict__ rdeg,
                        const unsigned short* __restrict__ H, unsigned short* __restrict__ NS) {
    int node = blockIdx.x * 4 + (threadIdx.x >> 6);
    if (node >= N_NODES) return;
    int lane = threadIdx.x & 63;
    int lo = rowptr[node], hi = rowptr[node + 1];
    float r = rdeg[node];
    if (D == 256) {
        const uint2* H2 = reinterpret_cast<const uint2*>(H);
        float a0 = 0.f, a1 = 0.f, a2 = 0.f, a3 = 0.f;
        int j = lo;
        for (; j + 1 < hi; j += 2) {
            uint2 v0 = H2[(size_t)csr[j] * 64 + lane];
            uint2 v1 = H2[(size_t)csr[j + 1] * 64 + lane];
            a0 += bf2f(v0.x & 0xFFFF) + bf2f(v1.x & 0xFFFF);
            a1 += bf2f(v0.x >> 16)    + bf2f(v1.x >> 16);
            a2 += bf2f(v0.y & 0xFFFF) + bf2f(v1.y & 0xFFFF);
            a3 += bf2f(v0.y >> 16)    + bf2f(v1.y >> 16);
        }
        if (j < hi) {
            uint2 v0 = H2[(size_t)csr[j] * 64 + lane];
            a0 += bf2f(v0.x & 0xFFFF); a1 += bf2f(v0.x >> 16);
            a2 += bf2f(v0.y & 0xFFFF); a3 += bf2f(v0.y >> 16);
        }
        uint2 o;
        o.x = (unsigned int)f2bf(a0 * r) | ((unsigned int)f2bf(a1 * r) << 16);
        o.y = (unsigned int)f2bf(a2 * r) | ((unsigned int)f2bf(a3 * r) << 16);
        reinterpret_cast<uint2*>(NS)[(size_t)node * 64 + lane] = o;
    } else {
        const unsigned int* H1 = reinterpret_cast<const unsigned int*>(H);
        float a0 = 0.f, a1 = 0.f;
        int j = lo;
        for (; j + 1 < hi; j += 2) {
            unsigned int v0 = H1[(size_t)csr[j] * 64 + lane];
            unsigned int v1 = H1[(size_t)csr[j + 1] * 64 + lane];
            a0 += bf2f(v0 & 0xFFFF) + bf2f(v1 & 0xFFFF);
            a1 += bf2f(v0 >> 16)    + bf2f(v1 >> 16);
        }
        if (j < hi) {
            unsigned int v0 = H1[(size_t)csr[j] * 64 + lane];
            a0 += bf2f(v0 & 0xFFFF); a1 += bf2f(v0 >> 16);
        }
        unsigned int o = (unsigned int)f2bf(a0 * r) | ((unsigned int)f2bf(a1 * r) << 16);
        reinterpret_cast<unsigned int*>(NS)[(size_t)node * 64 + lane] = o;
    }
}

// ---------------- MFMA GEMM: OUT = elu( [X|NS] @ Wt^T + b ), Wt is [256][2D] bf16 ----------------
// block tile 128 rows x 256 cols, 8 waves (2x4), wave tile 64x64, BK=64
template<int D>
__global__ __launch_bounds__(512)
void gemm_mfma_kernel(const unsigned short* __restrict__ X, const unsigned short* __restrict__ NS,
                      const unsigned short* __restrict__ Wt, const float* __restrict__ bias,
                      unsigned short* __restrict__ OUT) {
    constexpr int KTOT = 2 * D;
    __shared__ __align__(16) unsigned short A_lds[128 * 64];
    __shared__ __align__(16) unsigned short B_lds[256 * 64];
    const int tid = threadIdx.x;
    const int lane = tid & 63;
    const int wid = tid >> 6;
    const int wm = wid >> 2, wn = wid & 3;
    const int rowbase = blockIdx.x * 128;

    f32x4 acc[4][4];
    #pragma unroll
    for (int i = 0; i < 4; ++i)
        #pragma unroll
        for (int j = 0; j < 4; ++j) acc[i][j] = (f32x4)0.0f;

    for (int kt = 0; kt < KTOT; kt += 64) {
        const unsigned short* Aseg = (kt < D) ? X : NS;
        const int kd0 = (kt < D) ? kt : kt - D;
        // stage A tile [128][64] bf16, swizzled via pre-swizzled global source (linear LDS dest)
        #pragma unroll
        for (int p = 0; p < 2; ++p) {
            int c = (p * 8 + wid) * 64 + lane;
            int row = c >> 3, sl = c & 7;
            int ss = sl ^ (row & 7);
            const unsigned short* g = Aseg + (size_t)(rowbase + row) * D + kd0 + ss * 8;
            unsigned short* l = &A_lds[(size_t)(p * 8 + wid) * 512];
            __builtin_amdgcn_global_load_lds((const __attribute__((address_space(1))) unsigned int*)g,
                                             (__attribute__((address_space(3))) unsigned int*)l, 16, 0, 0);
        }
        // stage B tile: Bt[col][64] from Wt rows
        #pragma unroll
        for (int p = 0; p < 4; ++p) {
            int c = (p * 8 + wid) * 64 + lane;
            int br = c >> 3, sl = c & 7;
            int ss = sl ^ (br & 7);
            const unsigned short* g = Wt + (size_t)br * KTOT + kt + ss * 8;
            unsigned short* l = &B_lds[(size_t)(p * 8 + wid) * 512];
            __builtin_amdgcn_global_load_lds((const __attribute__((address_space(1))) unsigned int*)g,
                                             (__attribute__((address_space(3))) unsigned int*)l, 16, 0, 0);
        }
        __syncthreads();
        #pragma unroll
        for (int ks = 0; ks < 2; ++ks) {
            short8 a[4], b[4];
            int s = ks * 4 + (lane >> 4);
            #pragma unroll
            for (int f = 0; f < 4; ++f) {
                int row = wm * 64 + f * 16 + (lane & 15);
                a[f] = *reinterpret_cast<const short8*>(&A_lds[row * 64 + ((s ^ (row & 7)) << 3)]);
                int col = wn * 64 + f * 16 + (lane & 15);
                b[f] = *reinterpret_cast<const short8*>(&B_lds[col * 64 + ((s ^ (col & 7)) << 3)]);
            }
            #pragma unroll
            for (int fi = 0; fi < 4; ++fi)
                #pragma unroll
                for (int fj = 0; fj < 4; ++fj)
                    acc[fi][fj] = __builtin_amdgcn_mfma_f32_16x16x32_bf16(a[fi], b[fj], acc[fi][fj], 0, 0, 0);
        }
        __syncthreads();
    }

    float bv[4];
    #pragma unroll
    for (int fj = 0; fj < 4; ++fj) bv[fj] = bias[wn * 64 + fj * 16 + (lane & 15)];
    #pragma unroll
    for (int fi = 0; fi < 4; ++fi) {
        #pragma unroll
        for (int r = 0; r < 4; ++r) {
            int row = rowbase + wm * 64 + fi * 16 + (lane >> 4) * 4 + r;
            if (row < N_NODES) {
                #pragma unroll
                for (int fj = 0; fj < 4; ++fj) {
                    float z = acc[fi][fj][r] + bv[fj];
                    z = z > 0.f ? z : (expf(z) - 1.f);
                    OUT[(size_t)row * 256 + wn * 64 + fj * 16 + (lane & 15)] = f2bf(z);
                }
            }
        }
    }
}

// ---------------- fixup for degree-0 rows: OUT[row] = elu(X[row] @ Wg + b) ----------------
template<typename T, int D>
__global__ void fixup_kernel(const int* __restrict__ cnt, const int* __restrict__ list,
                             const T* __restrict__ X,
                             const float* __restrict__ Wg, const float* __restrict__ bias,
                             unsigned short* __restrict__ OUT) {
    int c = threadIdx.x;
    int n = *cnt;
    for (int i = blockIdx.x; i < n; i += gridDim.x) {
        int row = list[i];
        float acc = bias[c];
        for (int k = 0; k < D; ++k) {
            float xv;
            if constexpr (sizeof(T) == 4) xv = ((const float*)X)[(size_t)row * D + k];
            else                          xv = bf2f(((const unsigned short*)X)[(size_t)row * D + k]);
            acc = fmaf(xv, Wg[(size_t)k * 256 + c], acc);
        }
        acc = acc > 0.f ? acc : (expf(acc) - 1.f);
        OUT[(size_t)row * 256 + c] = f2bf(acc);
    }
}

// ---------------- mean pool per graph + classifier (bf16 H) ----------------
__global__ void pool_classify_kernel(const unsigned short* __restrict__ H, const int* __restrict__ batch,
                                     const float* __restrict__ Wc, const float* __restrict__ bc,
                                     float* __restrict__ out) {
    __shared__ int s_lo, s_hi;
    __shared__ float pooled[HIDDEN];
    int g = blockIdx.x;
    if (threadIdx.x == 0) {
        int lo = 0, hi = N_NODES;
        while (lo < hi) { int m = (lo + hi) >> 1; if (batch[m] < g) lo = m + 1; else hi = m; }
        s_lo = lo;
        int lo2 = lo, hi2 = N_NODES;
        while (lo2 < hi2) { int m = (lo2 + hi2) >> 1; if (batch[m] < g + 1) lo2 = m + 1; else hi2 = m; }
        s_hi = lo2;
    }
    __syncthreads();
    int lo = s_lo, hi = s_hi;
    int t = threadIdx.x;
    float sum = 0.0f;
    for (int r = lo; r < hi; ++r) sum += bf2f(H[(size_t)r * HIDDEN + t]);
    float cnt = (float)(hi - lo);
    pooled[t] = sum / fmaxf(cnt, 1.0f);
    __syncthreads();
    if (t < N_CLASSES) {
        float accv = bc[t];
        #pragma unroll 4
        for (int k = 0; k < HIDDEN; ++k) accv = fmaf(pooled[k], Wc[k * N_CLASSES + t], accv);
        out[g * N_CLASSES + t] = accv;
    }
}

extern "C" void kernel_launch(void* const* d_in, const int* in_sizes, int n_in,
                              void* d_out, int out_size, void* d_ws, size_t ws_size,
                              hipStream_t stream) {
    const float* x    = (const float*)d_in[0];
    const int*   ei   = (const int*)d_in[1];
    const int*   batch= (const int*)d_in[2];
    const float* Wg0  = (const float*)d_in[3];
    const float* Wl0  = (const float*)d_in[4];
    const float* Ws0  = (const float*)d_in[5];
    const float* b0   = (const float*)d_in[6];
    const float* Wg1  = (const float*)d_in[7];
    const float* Wl1  = (const float*)d_in[8];
    const float* Ws1  = (const float*)d_in[9];
    const float* b1   = (const float*)d_in[10];
    const float* Wc   = (const float*)d_in[11];
    const float* bc   = (const float*)d_in[12];
    const int* src = ei;
    const int* dst = ei + N_EDGES;

    char* ws = (char*)d_ws;
    // workspace layout (byte offsets, all 16B aligned)
    int*            deg    = (int*)(ws + 0);               // [N_PAD]
    int*            d0cnt  = (int*)(ws + 200192);          // 1 int (inside memset region)
    float*          rdeg   = (float*)(ws + 262144);
    int*            rowptr = (int*)(ws + 524288);
    int*            cursor = (int*)(ws + 786432);
    int*            csr    = (int*)(ws + 1048576);         // [800000]
    int*            d0list = (int*)(ws + 4259840);         // [50000]
    unsigned short* x_bf   = (unsigned short*)(ws + 4521984);    // [N_PAD][128]
    unsigned short* ns0_bf = (unsigned short*)(ws + 17334272);   // [N_PAD][128]
    unsigned short* h1_bf  = (unsigned short*)(ws + 30146560);   // [N_PAD][256]
    unsigned short* ns1_bf = (unsigned short*)(ws + 55771136);   // [N_PAD][256]
    unsigned short* h2_bf  = (unsigned short*)(ws + 81395712);   // [N_PAD][256]
    unsigned short* Wt0    = (unsigned short*)(ws + 107020288);  // [256][256]
    unsigned short* Wt1    = (unsigned short*)(ws + 107151360);  // [256][512]

    // zero degree counts + d0cnt
    hipMemsetAsync(ws, 0, 262144, stream);

    // CSR build
    deg_count_kernel<<<(N_EDGES + 255) / 256, 256, 0, stream>>>(src, deg);
    scan_kernel<<<1, 1024, 0, stream>>>(deg, rowptr, cursor, rdeg, d0cnt, d0list);
    csr_fill_kernel<<<(N_EDGES + 255) / 256, 256, 0, stream>>>(src, dst, cursor, csr);

    // weight prep + x conversion
    prep_w_kernel<IN_DIM><<<(256 * 2 * IN_DIM + 255) / 256, 256, 0, stream>>>(Wg0, Wl0, Ws0, Wt0);
    prep_w_kernel<HIDDEN><<<(256 * 2 * HIDDEN + 255) / 256, 256, 0, stream>>>(Wg1, Wl1, Ws1, Wt1);
    cvt_bf16_kernel<<<(N_NODES * IN_DIM / 4 + 255) / 256, 256, 0, stream>>>(x, x_bf, N_NODES * IN_DIM / 4);

    // layer 0
    gather_mean_kernel<IN_DIM><<<(N_NODES + 3) / 4, 256, 0, stream>>>(rowptr, csr, rdeg, x_bf, ns0_bf);
    gemm_mfma_kernel<IN_DIM><<<(N_NODES + 127) / 128, 512, 0, stream>>>(x_bf, ns0_bf, Wt0, b0, h1_bf);
    fixup_kernel<float, IN_DIM><<<64, 256, 0, stream>>>(d0cnt, d0list, x, Wg0, b0, h1_bf);

    // layer 1
    gather_mean_kernel<HIDDEN><<<(N_NODES + 3) / 4, 256, 0, stream>>>(rowptr, csr, rdeg, h1_bf, ns1_bf);
    gemm_mfma_kernel<HIDDEN><<<(N_NODES + 127) / 128, 512, 0, stream>>>(h1_bf, ns1_bf, Wt1, b1, h2_bf);
    fixup_kernel<unsigned short, HIDDEN><<<64, 256, 0, stream>>>(d0cnt, d0list, h1_bf, Wg1, b1, h2_bf);

    // pool + classify
    pool_classify_kernel<<<N_GRAPHS, HIDDEN, 0, stream>>>(h2_bf, batch, Wc, bc, (float*)d_out);
}

// Round 4
// 404.751 us; speedup vs baseline: 11.9349x; 1.4228x over previous
//
#include <hip/hip_runtime.h>

#define N_NODES 50000
#define N_PAD   50048          // padded row count (multiple of 128)
#define N_EDGES 800000
#define IN_DIM 128
#define HIDDEN 256
#define N_CLASSES 10
#define N_GRAPHS 64

typedef __attribute__((ext_vector_type(8))) short short8;
typedef __attribute__((ext_vector_type(4))) float f32x4;

__device__ __forceinline__ float bf2f(unsigned short h) {
    union { unsigned int u; float f; } v; v.u = ((unsigned int)h) << 16; return v.f;
}
__device__ __forceinline__ unsigned short f2bf(float f) {
    union { float f; unsigned int u; } v; v.f = f;
    unsigned int u = v.u;
    u += 0x7FFFu + ((u >> 16) & 1u);   // round to nearest even
    return (unsigned short)(u >> 16);
}

// ---------------- degree count ----------------
__global__ void deg_count_kernel(const int* __restrict__ src, int* __restrict__ deg) {
    int e = blockIdx.x * blockDim.x + threadIdx.x;
    if (e < N_EDGES) atomicAdd(&deg[src[e]], 1);
}

// ---------------- scan: rowptr, cursor, rdeg, deg0 list ----------------
__global__ __launch_bounds__(1024)
void scan_kernel(const int* __restrict__ deg, int* __restrict__ rowptr,
                 int* __restrict__ cursor, float* __restrict__ rdeg,
                 int* __restrict__ d0cnt, int* __restrict__ d0list) {
    __shared__ int buf[1024];
    __shared__ int carry;
    if (threadIdx.x == 0) { carry = 0; rowptr[0] = 0; }
    __syncthreads();
    for (int base = 0; base < N_NODES; base += 1024) {
        int i = base + threadIdx.x;
        int v = (i < N_NODES) ? deg[i] : 0;
        buf[threadIdx.x] = v;
        __syncthreads();
        #pragma unroll
        for (int off = 1; off < 1024; off <<= 1) {
            int t = (threadIdx.x >= off) ? buf[threadIdx.x - off] : 0;
            __syncthreads();
            buf[threadIdx.x] += t;
            __syncthreads();
        }
        int incl = buf[threadIdx.x] + carry;
        if (i < N_NODES) {
            rowptr[i + 1] = incl;
            cursor[i] = incl - v;
            rdeg[i] = (v > 0) ? 1.0f / (float)v : 0.0f;
            if (v == 0) { int p = atomicAdd(d0cnt, 1); d0list[p] = i; }
        }
        __syncthreads();
        if (threadIdx.x == 1023) carry = incl;
        __syncthreads();
    }
}

// ---------------- CSR fill ----------------
__global__ void csr_fill_kernel(const int* __restrict__ src, const int* __restrict__ dst,
                                int* __restrict__ cursor, int* __restrict__ csr) {
    int e = blockIdx.x * blockDim.x + threadIdx.x;
    if (e < N_EDGES) {
        int p = atomicAdd(&cursor[src[e]], 1);
        csr[p] = dst[e];
    }
}

// ---------------- fp32 -> bf16 convert (4 at a time) ----------------
__global__ void cvt_bf16_kernel(const float* __restrict__ in, unsigned short* __restrict__ out, int n4) {
    int i = blockIdx.x * blockDim.x + threadIdx.x;
    if (i >= n4) return;
    float4 v = reinterpret_cast<const float4*>(in)[i];
    ushort4 o;
    o.x = f2bf(v.x); o.y = f2bf(v.y); o.z = f2bf(v.z); o.w = f2bf(v.w);
    reinterpret_cast<ushort4*>(out)[i] = o;
}

// ---------------- weight prep: Wt[c][k] = bf16( k<D ? Wg[k][c]+Ws[k][c] : Wl[k-D][c] ) ----------------
template<int D>
__global__ void prep_w_kernel(const float* __restrict__ Wg, const float* __restrict__ Wl,
                              const float* __restrict__ Ws, unsigned short* __restrict__ Wt) {
    int i = blockIdx.x * blockDim.x + threadIdx.x;
    if (i >= 256 * 2 * D) return;
    int c = i / (2 * D), k = i % (2 * D);
    float v;
    if (k < D) v = Wg[(size_t)k * 256 + c] + Ws[(size_t)k * 256 + c];
    else       v = Wl[(size_t)(k - D) * 256 + c];
    Wt[i] = f2bf(v);
}

// ---------------- gather mean (bf16 in, bf16 out), one wave per node ----------------
template<int D>
__global__ __launch_bounds__(256)
void gather_mean_kernel(const int* __restrict__ rowptr, const int* __restrict__ csr,
                        const float* __restrict__ rdeg,
                        const unsigned short* __restrict__ H, unsigned short* __restrict__ NS) {
    int node = blockIdx.x * 4 + (threadIdx.x >> 6);
    if (node >= N_NODES) return;
    int lane = threadIdx.x & 63;
    int lo = rowptr[node], hi = rowptr[node + 1];
    float r = rdeg[node];
    if (D == 256) {
        const uint2* H2 = reinterpret_cast<const uint2*>(H);
        float a0 = 0.f, a1 = 0.f, a2 = 0.f, a3 = 0.f;
        int j = lo;
        for (; j + 1 < hi; j += 2) {
            uint2 v0 = H2[(size_t)csr[j] * 64 + lane];
            uint2 v1 = H2[(size_t)csr[j + 1] * 64 + lane];
            a0 += bf2f(v0.x & 0xFFFF) + bf2f(v1.x & 0xFFFF);
            a1 += bf2f(v0.x >> 16)    + bf2f(v1.x >> 16);
            a2 += bf2f(v0.y & 0xFFFF) + bf2f(v1.y & 0xFFFF);
            a3 += bf2f(v0.y >> 16)    + bf2f(v1.y >> 16);
        }
        if (j < hi) {
            uint2 v0 = H2[(size_t)csr[j] * 64 + lane];
            a0 += bf2f(v0.x & 0xFFFF); a1 += bf2f(v0.x >> 16);
            a2 += bf2f(v0.y & 0xFFFF); a3 += bf2f(v0.y >> 16);
        }
        uint2 o;
        o.x = (unsigned int)f2bf(a0 * r) | ((unsigned int)f2bf(a1 * r) << 16);
        o.y = (unsigned int)f2bf(a2 * r) | ((unsigned int)f2bf(a3 * r) << 16);
        reinterpret_cast<uint2*>(NS)[(size_t)node * 64 + lane] = o;
    } else {
        const unsigned int* H1 = reinterpret_cast<const unsigned int*>(H);
        float a0 = 0.f, a1 = 0.f;
        int j = lo;
        for (; j + 1 < hi; j += 2) {
            unsigned int v0 = H1[(size_t)csr[j] * 64 + lane];
            unsigned int v1 = H1[(size_t)csr[j + 1] * 64 + lane];
            a0 += bf2f(v0 & 0xFFFF) + bf2f(v1 & 0xFFFF);
            a1 += bf2f(v0 >> 16)    + bf2f(v1 >> 16);
        }
        if (j < hi) {
            unsigned int v0 = H1[(size_t)csr[j] * 64 + lane];
            a0 += bf2f(v0 & 0xFFFF); a1 += bf2f(v0 >> 16);
        }
        unsigned int o = (unsigned int)f2bf(a0 * r) | ((unsigned int)f2bf(a1 * r) << 16);
        reinterpret_cast<unsigned int*>(NS)[(size_t)node * 64 + lane] = o;
    }
}

// ---------------- MFMA GEMM: OUT = elu( [X|NS] @ Wt^T + b ), Wt is [256][2D] bf16 ----------------
template<int D>
__global__ __launch_bounds__(512)
void gemm_mfma_kernel(const unsigned short* __restrict__ X, const unsigned short* __restrict__ NS,
                      const unsigned short* __restrict__ Wt, const float* __restrict__ bias,
                      unsigned short* __restrict__ OUT) {
    constexpr int KTOT = 2 * D;
    __shared__ __align__(16) unsigned short A_lds[128 * 64];
    __shared__ __align__(16) unsigned short B_lds[256 * 64];
    const int tid = threadIdx.x;
    const int lane = tid & 63;
    const int wid = tid >> 6;
    const int wm = wid >> 2, wn = wid & 3;
    const int rowbase = blockIdx.x * 128;

    f32x4 acc[4][4];
    #pragma unroll
    for (int i = 0; i < 4; ++i)
        #pragma unroll
        for (int j = 0; j < 4; ++j) acc[i][j] = (f32x4)0.0f;

    for (int kt = 0; kt < KTOT; kt += 64) {
        const unsigned short* Aseg = (kt < D) ? X : NS;
        const int kd0 = (kt < D) ? kt : kt - D;
        #pragma unroll
        for (int p = 0; p < 2; ++p) {
            int c = (p * 8 + wid) * 64 + lane;
            int row = c >> 3, sl = c & 7;
            int ss = sl ^ (row & 7);
            const unsigned short* g = Aseg + (size_t)(rowbase + row) * D + kd0 + ss * 8;
            unsigned short* l = &A_lds[(size_t)(p * 8 + wid) * 512];
            __builtin_amdgcn_global_load_lds((const __attribute__((address_space(1))) unsigned int*)g,
                                             (__attribute__((address_space(3))) unsigned int*)l, 16, 0, 0);
        }
        #pragma unroll
        for (int p = 0; p < 4; ++p) {
            int c = (p * 8 + wid) * 64 + lane;
            int br = c >> 3, sl = c & 7;
            int ss = sl ^ (br & 7);
            const unsigned short* g = Wt + (size_t)br * KTOT + kt + ss * 8;
            unsigned short* l = &B_lds[(size_t)(p * 8 + wid) * 512];
            __builtin_amdgcn_global_load_lds((const __attribute__((address_space(1))) unsigned int*)g,
                                             (__attribute__((address_space(3))) unsigned int*)l, 16, 0, 0);
        }
        __syncthreads();
        #pragma unroll
        for (int ks = 0; ks < 2; ++ks) {
            short8 a[4], b[4];
            int s = ks * 4 + (lane >> 4);
            #pragma unroll
            for (int f = 0; f < 4; ++f) {
                int row = wm * 64 + f * 16 + (lane & 15);
                a[f] = *reinterpret_cast<const short8*>(&A_lds[row * 64 + ((s ^ (row & 7)) << 3)]);
                int col = wn * 64 + f * 16 + (lane & 15);
                b[f] = *reinterpret_cast<const short8*>(&B_lds[col * 64 + ((s ^ (col & 7)) << 3)]);
            }
            #pragma unroll
            for (int fi = 0; fi < 4; ++fi)
                #pragma unroll
                for (int fj = 0; fj < 4; ++fj)
                    acc[fi][fj] = __builtin_amdgcn_mfma_f32_16x16x32_bf16(a[fi], b[fj], acc[fi][fj], 0, 0, 0);
        }
        __syncthreads();
    }

    float bv[4];
    #pragma unroll
    for (int fj = 0; fj < 4; ++fj) bv[fj] = bias[wn * 64 + fj * 16 + (lane & 15)];
    #pragma unroll
    for (int fi = 0; fi < 4; ++fi) {
        #pragma unroll
        for (int r = 0; r < 4; ++r) {
            int row = rowbase + wm * 64 + fi * 16 + (lane >> 4) * 4 + r;
            if (row < N_NODES) {
                #pragma unroll
                for (int fj = 0; fj < 4; ++fj) {
                    float z = acc[fi][fj][r] + bv[fj];
                    z = z > 0.f ? z : (expf(z) - 1.f);
                    OUT[(size_t)row * 256 + wn * 64 + fj * 16 + (lane & 15)] = f2bf(z);
                }
            }
        }
    }
}

// ---------------- fixup for degree-0 rows: OUT[row] = elu(X[row] @ Wg + b) ----------------
template<typename T, int D>
__global__ void fixup_kernel(const int* __restrict__ cnt, const int* __restrict__ list,
                             const T* __restrict__ X,
                             const float* __restrict__ Wg, const float* __restrict__ bias,
                             unsigned short* __restrict__ OUT) {
    int c = threadIdx.x;
    int n = *cnt;
    for (int i = blockIdx.x; i < n; i += gridDim.x) {
        int row = list[i];
        float acc = bias[c];
        for (int k = 0; k < D; ++k) {
            float xv;
            if constexpr (sizeof(T) == 4) xv = ((const float*)X)[(size_t)row * D + k];
            else                          xv = bf2f(((const unsigned short*)X)[(size_t)row * D + k]);
            acc = fmaf(xv, Wg[(size_t)k * 256 + c], acc);
        }
        acc = acc > 0.f ? acc : (expf(acc) - 1.f);
        OUT[(size_t)row * 256 + c] = f2bf(acc);
    }
}

// ---------------- pooling stage 1: per-block segmented accumulate -> atomicAdd ----------------
__global__ __launch_bounds__(256)
void pool_partial_kernel(const unsigned short* __restrict__ H, const int* __restrict__ batch,
                         float* __restrict__ pooled) {
    const int base = blockIdx.x * 64;
    const int t = threadIdx.x;
    float acc = 0.0f;
    int cur = batch[base];
    const int end = (base + 64 < N_NODES) ? base + 64 : N_NODES;
    for (int r = base; r < end; ++r) {
        int g = batch[r];          // uniform across block, cached
        if (g != cur) {
            atomicAdd(&pooled[cur * HIDDEN + t], acc);
            acc = 0.0f; cur = g;
        }
        acc += bf2f(H[(size_t)r * HIDDEN + t]);
    }
    atomicAdd(&pooled[cur * HIDDEN + t], acc);
}

// ---------------- pooling stage 2: divide + classifier ----------------
__global__ void classify_kernel(const float* __restrict__ pooled, const int* __restrict__ batch,
                                const float* __restrict__ Wc, const float* __restrict__ bc,
                                float* __restrict__ out) {
    __shared__ int s_lo, s_hi;
    __shared__ float pl[HIDDEN];
    int g = blockIdx.x;
    if (threadIdx.x == 0) {
        int lo = 0, hi = N_NODES;
        while (lo < hi) { int m = (lo + hi) >> 1; if (batch[m] < g) lo = m + 1; else hi = m; }
        s_lo = lo;
        int lo2 = lo, hi2 = N_NODES;
        while (lo2 < hi2) { int m = (lo2 + hi2) >> 1; if (batch[m] < g + 1) lo2 = m + 1; else hi2 = m; }
        s_hi = lo2;
    }
    __syncthreads();
    int t = threadIdx.x;
    float cnt = (float)(s_hi - s_lo);
    pl[t] = pooled[g * HIDDEN + t] / fmaxf(cnt, 1.0f);
    __syncthreads();
    if (t < N_CLASSES) {
        float accv = bc[t];
        #pragma unroll 4
        for (int k = 0; k < HIDDEN; ++k) accv = fmaf(pl[k], Wc[k * N_CLASSES + t], accv);
        out[g * N_CLASSES + t] = accv;
    }
}

extern "C" void kernel_launch(void* const* d_in, const int* in_sizes, int n_in,
                              void* d_out, int out_size, void* d_ws, size_t ws_size,
                              hipStream_t stream) {
    const float* x    = (const float*)d_in[0];
    const int*   ei   = (const int*)d_in[1];
    const int*   batch= (const int*)d_in[2];
    const float* Wg0  = (const float*)d_in[3];
    const float* Wl0  = (const float*)d_in[4];
    const float* Ws0  = (const float*)d_in[5];
    const float* b0   = (const float*)d_in[6];
    const float* Wg1  = (const float*)d_in[7];
    const float* Wl1  = (const float*)d_in[8];
    const float* Ws1  = (const float*)d_in[9];
    const float* b1   = (const float*)d_in[10];
    const float* Wc   = (const float*)d_in[11];
    const float* bc   = (const float*)d_in[12];
    const int* src = ei;
    const int* dst = ei + N_EDGES;

    char* ws = (char*)d_ws;
    int*            deg    = (int*)(ws + 0);               // [N_PAD]
    int*            d0cnt  = (int*)(ws + 200192);          // 1 int (inside memset region)
    float*          rdeg   = (float*)(ws + 262144);
    int*            rowptr = (int*)(ws + 524288);
    int*            cursor = (int*)(ws + 786432);          // dead after csr_fill
    float*          pooled = (float*)(ws + 786432);        // aliases cursor: f32[64*256] = 64KB
    int*            csr    = (int*)(ws + 1048576);         // [800000]
    int*            d0list = (int*)(ws + 4259840);         // [50000]
    unsigned short* x_bf   = (unsigned short*)(ws + 4521984);    // [N_PAD][128]
    unsigned short* ns0_bf = (unsigned short*)(ws + 17334272);   // [N_PAD][128]
    unsigned short* h1_bf  = (unsigned short*)(ws + 30146560);   // [N_PAD][256]
    unsigned short* ns1_bf = (unsigned short*)(ws + 55771136);   // [N_PAD][256]
    unsigned short* h2_bf  = (unsigned short*)(ws + 81395712);   // [N_PAD][256]
    unsigned short* Wt0    = (unsigned short*)(ws + 107020288);  // [256][256]
    unsigned short* Wt1    = (unsigned short*)(ws + 107151360);  // [256][512]

    // zero degree counts + d0cnt
    hipMemsetAsync(ws, 0, 262144, stream);

    // CSR build
    deg_count_kernel<<<(N_EDGES + 255) / 256, 256, 0, stream>>>(src, deg);
    scan_kernel<<<1, 1024, 0, stream>>>(deg, rowptr, cursor, rdeg, d0cnt, d0list);
    csr_fill_kernel<<<(N_EDGES + 255) / 256, 256, 0, stream>>>(src, dst, cursor, csr);

    // weight prep + x conversion
    prep_w_kernel<IN_DIM><<<(256 * 2 * IN_DIM + 255) / 256, 256, 0, stream>>>(Wg0, Wl0, Ws0, Wt0);
    prep_w_kernel<HIDDEN><<<(256 * 2 * HIDDEN + 255) / 256, 256, 0, stream>>>(Wg1, Wl1, Ws1, Wt1);
    cvt_bf16_kernel<<<(N_NODES * IN_DIM / 4 + 255) / 256, 256, 0, stream>>>(x, x_bf, N_NODES * IN_DIM / 4);

    // layer 0
    gather_mean_kernel<IN_DIM><<<(N_NODES + 3) / 4, 256, 0, stream>>>(rowptr, csr, rdeg, x_bf, ns0_bf);
    gemm_mfma_kernel<IN_DIM><<<(N_NODES + 127) / 128, 512, 0, stream>>>(x_bf, ns0_bf, Wt0, b0, h1_bf);
    fixup_kernel<float, IN_DIM><<<64, 256, 0, stream>>>(d0cnt, d0list, x, Wg0, b0, h1_bf);

    // layer 1
    gather_mean_kernel<HIDDEN><<<(N_NODES + 3) / 4, 256, 0, stream>>>(rowptr, csr, rdeg, h1_bf, ns1_bf);
    gemm_mfma_kernel<HIDDEN><<<(N_NODES + 127) / 128, 512, 0, stream>>>(h1_bf, ns1_bf, Wt1, b1, h2_bf);
    fixup_kernel<unsigned short, HIDDEN><<<64, 256, 0, stream>>>(d0cnt, d0list, h1_bf, Wg1, b1, h2_bf);

    // pool (cursor buffer is dead by now; pooled aliases it)
    hipMemsetAsync(pooled, 0, N_GRAPHS * HIDDEN * sizeof(float), stream);
    pool_partial_kernel<<<(N_NODES + 63) / 64, 256, 0, stream>>>(h2_bf, batch, pooled);
    classify_kernel<<<N_GRAPHS, HIDDEN, 0, stream>>>(pooled, batch, Wc, bc, (float*)d_out);
}

// Round 5
// 325.278 us; speedup vs baseline: 14.8509x; 1.2443x over previous
//
#include <hip/hip_runtime.h>

#define N_NODES 50000
#define N_PAD   50048          // padded row count (multiple of 128)
#define N_EDGES 800000
#define IN_DIM 128
#define HIDDEN 256
#define N_CLASSES 10
#define N_GRAPHS 64

#define SCAN_BLK 1024
#define NB_SCAN ((N_NODES + SCAN_BLK - 1) / SCAN_BLK)   // 49

typedef __attribute__((ext_vector_type(8))) short short8;
typedef __attribute__((ext_vector_type(4))) float f32x4;

__device__ __forceinline__ float bf2f(unsigned short h) {
    union { unsigned int u; float f; } v; v.u = ((unsigned int)h) << 16; return v.f;
}
__device__ __forceinline__ unsigned short f2bf(float f) {
    union { float f; unsigned int u; } v; v.f = f;
    unsigned int u = v.u;
    u += 0x7FFFu + ((u >> 16) & 1u);   // round to nearest even
    return (unsigned short)(u >> 16);
}

// ---------------- degree count ----------------
__global__ void deg_count_kernel(const int* __restrict__ src, int* __restrict__ deg) {
    int e = blockIdx.x * blockDim.x + threadIdx.x;
    if (e < N_EDGES) atomicAdd(&deg[src[e]], 1);
}

// ---------------- multi-block scan, phase A: per-block sums ----------------
__global__ __launch_bounds__(SCAN_BLK)
void block_sum_kernel(const int* __restrict__ deg, int* __restrict__ blocksum) {
    __shared__ int red[SCAN_BLK / 64];
    int i = blockIdx.x * SCAN_BLK + threadIdx.x;
    int v = (i < N_NODES) ? deg[i] : 0;
    #pragma unroll
    for (int off = 32; off; off >>= 1) v += __shfl_down(v, off, 64);
    if ((threadIdx.x & 63) == 0) red[threadIdx.x >> 6] = v;
    __syncthreads();
    if (threadIdx.x < 64) {
        int s = (threadIdx.x < SCAN_BLK / 64) ? red[threadIdx.x] : 0;
        #pragma unroll
        for (int off = 8; off; off >>= 1) s += __shfl_down(s, off, 64);
        if (threadIdx.x == 0) blocksum[blockIdx.x] = s;
    }
}

// ---------------- phase B: exclusive scan of block sums (one wave) ----------------
__global__ void block_offset_kernel(const int* __restrict__ blocksum, int* __restrict__ blockoff) {
    int lane = threadIdx.x;   // 64 threads
    int v = (lane < NB_SCAN) ? blocksum[lane] : 0;
    #pragma unroll
    for (int off = 1; off < 64; off <<= 1) {
        int t = __shfl_up(v, off, 64);
        if (lane >= off) v += t;
    }
    int ex = __shfl_up(v, 1, 64);
    if (lane == 0) ex = 0;
    if (lane < NB_SCAN) blockoff[lane] = ex;
}

// ---------------- phase C: local scan + outputs ----------------
__global__ __launch_bounds__(SCAN_BLK)
void scan_phase_c_kernel(const int* __restrict__ deg, const int* __restrict__ blockoff,
                         int* __restrict__ rowptr, int* __restrict__ cursor,
                         float* __restrict__ rdeg,
                         int* __restrict__ d0cnt, int* __restrict__ d0list) {
    __shared__ int buf[SCAN_BLK];
    int i = blockIdx.x * SCAN_BLK + threadIdx.x;
    int v = (i < N_NODES) ? deg[i] : 0;
    buf[threadIdx.x] = v;
    __syncthreads();
    #pragma unroll
    for (int off = 1; off < SCAN_BLK; off <<= 1) {
        int t = (threadIdx.x >= off) ? buf[threadIdx.x - off] : 0;
        __syncthreads();
        buf[threadIdx.x] += t;
        __syncthreads();
    }
    int incl = buf[threadIdx.x] + blockoff[blockIdx.x];
    if (i < N_NODES) {
        rowptr[i + 1] = incl;
        cursor[i] = incl - v;
        rdeg[i] = (v > 0) ? 1.0f / (float)v : 0.0f;
        if (v == 0) { int p = atomicAdd(d0cnt, 1); d0list[p] = i; }
        if (i == 0) rowptr[0] = 0;
    }
}

// ---------------- CSR fill ----------------
__global__ void csr_fill_kernel(const int* __restrict__ src, const int* __restrict__ dst,
                                int* __restrict__ cursor, int* __restrict__ csr) {
    int e = blockIdx.x * blockDim.x + threadIdx.x;
    if (e < N_EDGES) {
        int p = atomicAdd(&cursor[src[e]], 1);
        csr[p] = dst[e];
    }
}

// ---------------- fp32 -> bf16 convert (4 at a time) ----------------
__global__ void cvt_bf16_kernel(const float* __restrict__ in, unsigned short* __restrict__ out, int n4) {
    int i = blockIdx.x * blockDim.x + threadIdx.x;
    if (i >= n4) return;
    float4 v = reinterpret_cast<const float4*>(in)[i];
    ushort4 o;
    o.x = f2bf(v.x); o.y = f2bf(v.y); o.z = f2bf(v.z); o.w = f2bf(v.w);
    reinterpret_cast<ushort4*>(out)[i] = o;
}

// ---------------- weight prep: Wt[c][k] = bf16( k<D ? Wg[k][c]+Ws[k][c] : Wl[k-D][c] ) ----------------
template<int D>
__global__ void prep_w_kernel(const float* __restrict__ Wg, const float* __restrict__ Wl,
                              const float* __restrict__ Ws, unsigned short* __restrict__ Wt) {
    int i = blockIdx.x * blockDim.x + threadIdx.x;
    if (i >= 256 * 2 * D) return;
    int c = i / (2 * D), k = i % (2 * D);
    float v;
    if (k < D) v = Wg[(size_t)k * 256 + c] + Ws[(size_t)k * 256 + c];
    else       v = Wl[(size_t)(k - D) * 256 + c];
    Wt[i] = f2bf(v);
}

// ---------------- gather mean (bf16 in, bf16 out), one wave per node ----------------
template<int D>
__global__ __launch_bounds__(256)
void gather_mean_kernel(const int* __restrict__ rowptr, const int* __restrict__ csr,
                        const float* __restrict__ rdeg,
                        const unsigned short* __restrict__ H, unsigned short* __restrict__ NS) {
    int node = blockIdx.x * 4 + (threadIdx.x >> 6);
    if (node >= N_NODES) return;
    int lane = threadIdx.x & 63;
    int lo = rowptr[node], hi = rowptr[node + 1];
    float r = rdeg[node];
    if (D == 256) {
        const uint2* H2 = reinterpret_cast<const uint2*>(H);
        float a0 = 0.f, a1 = 0.f, a2 = 0.f, a3 = 0.f;
        int j = lo;
        for (; j + 1 < hi; j += 2) {
            uint2 v0 = H2[(size_t)csr[j] * 64 + lane];
            uint2 v1 = H2[(size_t)csr[j + 1] * 64 + lane];
            a0 += bf2f(v0.x & 0xFFFF) + bf2f(v1.x & 0xFFFF);
            a1 += bf2f(v0.x >> 16)    + bf2f(v1.x >> 16);
            a2 += bf2f(v0.y & 0xFFFF) + bf2f(v1.y & 0xFFFF);
            a3 += bf2f(v0.y >> 16)    + bf2f(v1.y >> 16);
        }
        if (j < hi) {
            uint2 v0 = H2[(size_t)csr[j] * 64 + lane];
            a0 += bf2f(v0.x & 0xFFFF); a1 += bf2f(v0.x >> 16);
            a2 += bf2f(v0.y & 0xFFFF); a3 += bf2f(v0.y >> 16);
        }
        uint2 o;
        o.x = (unsigned int)f2bf(a0 * r) | ((unsigned int)f2bf(a1 * r) << 16);
        o.y = (unsigned int)f2bf(a2 * r) | ((unsigned int)f2bf(a3 * r) << 16);
        reinterpret_cast<uint2*>(NS)[(size_t)node * 64 + lane] = o;
    } else {
        const unsigned int* H1 = reinterpret_cast<const unsigned int*>(H);
        float a0 = 0.f, a1 = 0.f;
        int j = lo;
        for (; j + 1 < hi; j += 2) {
            unsigned int v0 = H1[(size_t)csr[j] * 64 + lane];
            unsigned int v1 = H1[(size_t)csr[j + 1] * 64 + lane];
            a0 += bf2f(v0 & 0xFFFF) + bf2f(v1 & 0xFFFF);
            a1 += bf2f(v0 >> 16)    + bf2f(v1 >> 16);
        }
        if (j < hi) {
            unsigned int v0 = H1[(size_t)csr[j] * 64 + lane];
            a0 += bf2f(v0 & 0xFFFF); a1 += bf2f(v0 >> 16);
        }
        unsigned int o = (unsigned int)f2bf(a0 * r) | ((unsigned int)f2bf(a1 * r) << 16);
        reinterpret_cast<unsigned int*>(NS)[(size_t)node * 64 + lane] = o;
    }
}

// ---------------- MFMA GEMM: OUT = elu( [X|NS] @ Wt^T + b ), Wt is [256][2D] bf16 ----------------
template<int D>
__global__ __launch_bounds__(512)
void gemm_mfma_kernel(const unsigned short* __restrict__ X, const unsigned short* __restrict__ NS,
                      const unsigned short* __restrict__ Wt, const float* __restrict__ bias,
                      unsigned short* __restrict__ OUT) {
    constexpr int KTOT = 2 * D;
    __shared__ __align__(16) unsigned short A_lds[128 * 64];
    __shared__ __align__(16) unsigned short B_lds[256 * 64];
    const int tid = threadIdx.x;
    const int lane = tid & 63;
    const int wid = tid >> 6;
    const int wm = wid >> 2, wn = wid & 3;
    const int rowbase = blockIdx.x * 128;

    f32x4 acc[4][4];
    #pragma unroll
    for (int i = 0; i < 4; ++i)
        #pragma unroll
        for (int j = 0; j < 4; ++j) acc[i][j] = (f32x4)0.0f;

    for (int kt = 0; kt < KTOT; kt += 64) {
        const unsigned short* Aseg = (kt < D) ? X : NS;
        const int kd0 = (kt < D) ? kt : kt - D;
        #pragma unroll
        for (int p = 0; p < 2; ++p) {
            int c = (p * 8 + wid) * 64 + lane;
            int row = c >> 3, sl = c & 7;
            int ss = sl ^ (row & 7);
            const unsigned short* g = Aseg + (size_t)(rowbase + row) * D + kd0 + ss * 8;
            unsigned short* l = &A_lds[(size_t)(p * 8 + wid) * 512];
            __builtin_amdgcn_global_load_lds((const __attribute__((address_space(1))) unsigned int*)g,
                                             (__attribute__((address_space(3))) unsigned int*)l, 16, 0, 0);
        }
        #pragma unroll
        for (int p = 0; p < 4; ++p) {
            int c = (p * 8 + wid) * 64 + lane;
            int br = c >> 3, sl = c & 7;
            int ss = sl ^ (br & 7);
            const unsigned short* g = Wt + (size_t)br * KTOT + kt + ss * 8;
            unsigned short* l = &B_lds[(size_t)(p * 8 + wid) * 512];
            __builtin_amdgcn_global_load_lds((const __attribute__((address_space(1))) unsigned int*)g,
                                             (__attribute__((address_space(3))) unsigned int*)l, 16, 0, 0);
        }
        __syncthreads();
        #pragma unroll
        for (int ks = 0; ks < 2; ++ks) {
            short8 a[4], b[4];
            int s = ks * 4 + (lane >> 4);
            #pragma unroll
            for (int f = 0; f < 4; ++f) {
                int row = wm * 64 + f * 16 + (lane & 15);
                a[f] = *reinterpret_cast<const short8*>(&A_lds[row * 64 + ((s ^ (row & 7)) << 3)]);
                int col = wn * 64 + f * 16 + (lane & 15);
                b[f] = *reinterpret_cast<const short8*>(&B_lds[col * 64 + ((s ^ (col & 7)) << 3)]);
            }
            #pragma unroll
            for (int fi = 0; fi < 4; ++fi)
                #pragma unroll
                for (int fj = 0; fj < 4; ++fj)
                    acc[fi][fj] = __builtin_amdgcn_mfma_f32_16x16x32_bf16(a[fi], b[fj], acc[fi][fj], 0, 0, 0);
        }
        __syncthreads();
    }

    float bv[4];
    #pragma unroll
    for (int fj = 0; fj < 4; ++fj) bv[fj] = bias[wn * 64 + fj * 16 + (lane & 15)];
    #pragma unroll
    for (int fi = 0; fi < 4; ++fi) {
        #pragma unroll
        for (int r = 0; r < 4; ++r) {
            int row = rowbase + wm * 64 + fi * 16 + (lane >> 4) * 4 + r;
            if (row < N_NODES) {
                #pragma unroll
                for (int fj = 0; fj < 4; ++fj) {
                    float z = acc[fi][fj][r] + bv[fj];
                    z = z > 0.f ? z : (expf(z) - 1.f);
                    OUT[(size_t)row * 256 + wn * 64 + fj * 16 + (lane & 15)] = f2bf(z);
                }
            }
        }
    }
}

// ---------------- fixup for degree-0 rows: OUT[row] = elu(X[row] @ Wg + b) ----------------
template<typename T, int D>
__global__ void fixup_kernel(const int* __restrict__ cnt, const int* __restrict__ list,
                             const T* __restrict__ X,
                             const float* __restrict__ Wg, const float* __restrict__ bias,
                             unsigned short* __restrict__ OUT) {
    int c = threadIdx.x;
    int n = *cnt;
    for (int i = blockIdx.x; i < n; i += gridDim.x) {
        int row = list[i];
        float acc = bias[c];
        for (int k = 0; k < D; ++k) {
            float xv;
            if constexpr (sizeof(T) == 4) xv = ((const float*)X)[(size_t)row * D + k];
            else                          xv = bf2f(((const unsigned short*)X)[(size_t)row * D + k]);
            acc = fmaf(xv, Wg[(size_t)k * 256 + c], acc);
        }
        acc = acc > 0.f ? acc : (expf(acc) - 1.f);
        OUT[(size_t)row * 256 + c] = f2bf(acc);
    }
}

// ---------------- pooling stage 1: per-block segmented accumulate -> atomicAdd ----------------
__global__ __launch_bounds__(256)
void pool_partial_kernel(const unsigned short* __restrict__ H, const int* __restrict__ batch,
                         float* __restrict__ pooled) {
    const int base = blockIdx.x * 64;
    const int t = threadIdx.x;
    float acc = 0.0f;
    int cur = batch[base];
    const int end = (base + 64 < N_NODES) ? base + 64 : N_NODES;
    for (int r = base; r < end; ++r) {
        int g = batch[r];
        if (g != cur) {
            atomicAdd(&pooled[cur * HIDDEN + t], acc);
            acc = 0.0f; cur = g;
        }
        acc += bf2f(H[(size_t)r * HIDDEN + t]);
    }
    atomicAdd(&pooled[cur * HIDDEN + t], acc);
}

// ---------------- pooling stage 2: divide + classifier ----------------
__global__ void classify_kernel(const float* __restrict__ pooled, const int* __restrict__ batch,
                                const float* __restrict__ Wc, const float* __restrict__ bc,
                                float* __restrict__ out) {
    __shared__ int s_lo, s_hi;
    __shared__ float pl[HIDDEN];
    int g = blockIdx.x;
    if (threadIdx.x == 0) {
        int lo = 0, hi = N_NODES;
        while (lo < hi) { int m = (lo + hi) >> 1; if (batch[m] < g) lo = m + 1; else hi = m; }
        s_lo = lo;
        int lo2 = lo, hi2 = N_NODES;
        while (lo2 < hi2) { int m = (lo2 + hi2) >> 1; if (batch[m] < g + 1) lo2 = m + 1; else hi2 = m; }
        s_hi = lo2;
    }
    __syncthreads();
    int t = threadIdx.x;
    float cnt = (float)(s_hi - s_lo);
    pl[t] = pooled[g * HIDDEN + t] / fmaxf(cnt, 1.0f);
    __syncthreads();
    if (t < N_CLASSES) {
        float accv = bc[t];
        #pragma unroll 4
        for (int k = 0; k < HIDDEN; ++k) accv = fmaf(pl[k], Wc[k * N_CLASSES + t], accv);
        out[g * N_CLASSES + t] = accv;
    }
}

extern "C" void kernel_launch(void* const* d_in, const int* in_sizes, int n_in,
                              void* d_out, int out_size, void* d_ws, size_t ws_size,
                              hipStream_t stream) {
    const float* x    = (const float*)d_in[0];
    const int*   ei   = (const int*)d_in[1];
    const int*   batch= (const int*)d_in[2];
    const float* Wg0  = (const float*)d_in[3];
    const float* Wl0  = (const float*)d_in[4];
    const float* Ws0  = (const float*)d_in[5];
    const float* b0   = (const float*)d_in[6];
    const float* Wg1  = (const float*)d_in[7];
    const float* Wl1  = (const float*)d_in[8];
    const float* Ws1  = (const float*)d_in[9];
    const float* b1   = (const float*)d_in[10];
    const float* Wc   = (const float*)d_in[11];
    const float* bc   = (const float*)d_in[12];
    const int* src = ei;
    const int* dst = ei + N_EDGES;

    char* ws = (char*)d_ws;
    int*            deg    = (int*)(ws + 0);               // [N_PAD]
    int*            d0cnt  = (int*)(ws + 200192);          // 1 int (inside memset region)
    int*            blocksum = (int*)(ws + 200704);        // [49]
    int*            blockoff = (int*)(ws + 201216);        // [49]
    float*          rdeg   = (float*)(ws + 262144);
    int*            rowptr = (int*)(ws + 524288);
    int*            cursor = (int*)(ws + 786432);          // dead after csr_fill
    float*          pooled = (float*)(ws + 786432);        // aliases cursor: f32[64*256] = 64KB
    int*            csr    = (int*)(ws + 1048576);         // [800000]
    int*            d0list = (int*)(ws + 4259840);         // [50000]
    unsigned short* x_bf   = (unsigned short*)(ws + 4521984);    // [N_PAD][128]
    unsigned short* ns0_bf = (unsigned short*)(ws + 17334272);   // [N_PAD][128]
    unsigned short* h1_bf  = (unsigned short*)(ws + 30146560);   // [N_PAD][256]
    unsigned short* ns1_bf = (unsigned short*)(ws + 55771136);   // [N_PAD][256]
    unsigned short* h2_bf  = (unsigned short*)(ws + 81395712);   // [N_PAD][256]
    unsigned short* Wt0    = (unsigned short*)(ws + 107020288);  // [256][256]
    unsigned short* Wt1    = (unsigned short*)(ws + 107151360);  // [256][512]

    // zero degree counts + d0cnt
    hipMemsetAsync(ws, 0, 262144, stream);

    // CSR build (multi-block scan)
    deg_count_kernel<<<(N_EDGES + 255) / 256, 256, 0, stream>>>(src, deg);
    block_sum_kernel<<<NB_SCAN, SCAN_BLK, 0, stream>>>(deg, blocksum);
    block_offset_kernel<<<1, 64, 0, stream>>>(blocksum, blockoff);
    scan_phase_c_kernel<<<NB_SCAN, SCAN_BLK, 0, stream>>>(deg, blockoff, rowptr, cursor, rdeg, d0cnt, d0list);
    csr_fill_kernel<<<(N_EDGES + 255) / 256, 256, 0, stream>>>(src, dst, cursor, csr);

    // weight prep + x conversion
    prep_w_kernel<IN_DIM><<<(256 * 2 * IN_DIM + 255) / 256, 256, 0, stream>>>(Wg0, Wl0, Ws0, Wt0);
    prep_w_kernel<HIDDEN><<<(256 * 2 * HIDDEN + 255) / 256, 256, 0, stream>>>(Wg1, Wl1, Ws1, Wt1);
    cvt_bf16_kernel<<<(N_NODES * IN_DIM / 4 + 255) / 256, 256, 0, stream>>>(x, x_bf, N_NODES * IN_DIM / 4);

    // layer 0
    gather_mean_kernel<IN_DIM><<<(N_NODES + 3) / 4, 256, 0, stream>>>(rowptr, csr, rdeg, x_bf, ns0_bf);
    gemm_mfma_kernel<IN_DIM><<<(N_NODES + 127) / 128, 512, 0, stream>>>(x_bf, ns0_bf, Wt0, b0, h1_bf);
    fixup_kernel<float, IN_DIM><<<64, 256, 0, stream>>>(d0cnt, d0list, x, Wg0, b0, h1_bf);

    // layer 1
    gather_mean_kernel<HIDDEN><<<(N_NODES + 3) / 4, 256, 0, stream>>>(rowptr, csr, rdeg, h1_bf, ns1_bf);
    gemm_mfma_kernel<HIDDEN><<<(N_NODES + 127) / 128, 512, 0, stream>>>(h1_bf, ns1_bf, Wt1, b1, h2_bf);
    fixup_kernel<unsigned short, HIDDEN><<<64, 256, 0, stream>>>(d0cnt, d0list, h1_bf, Wg1, b1, h2_bf);

    // pool (cursor buffer is dead by now; pooled aliases it)
    hipMemsetAsync(pooled, 0, N_GRAPHS * HIDDEN * sizeof(float), stream);
    pool_partial_kernel<<<(N_NODES + 63) / 64, 256, 0, stream>>>(h2_bf, batch, pooled);
    classify_kernel<<<N_GRAPHS, HIDDEN, 0, stream>>>(pooled, batch, Wc, bc, (float*)d_out);
}